// Round 13
// baseline (186.434 us; speedup 1.0000x reference)
//
#include <hip/hip_runtime.h>
#include <stdint.h>

using f32x4  = __attribute__((ext_vector_type(4))) float;
using bf16x8 = __attribute__((ext_vector_type(8))) short;
using ushort8 = __attribute__((ext_vector_type(8))) unsigned short;

#define B_   16384
#define S_   256
#define DIN  2048
#define DFC  1024
#define NB_  10

// f32 -> bf16 round-to-nearest-even
__device__ __forceinline__ unsigned short f2bf(float f) {
  union { float f; unsigned int u; } v; v.f = f;
  unsigned int u = v.u;
  unsigned int r = (u + 0x7FFFu + ((u >> 16) & 1u)) >> 16;
  return (unsigned short)r;
}

// async global->LDS, 16B per lane. LDS dest is wave-uniform base + lane*16;
// global source address is per-lane.
__device__ __forceinline__ void gload_lds16(const void* g, void* l) {
  __builtin_amdgcn_global_load_lds(
      (const __attribute__((address_space(1))) unsigned int*)g,
      (__attribute__((address_space(3))) unsigned int*)l, 16, 0, 0);
}

// epilogue-LDS swizzle (verified r11): chunk c of row r at pos c ^ SW(r&15).
__device__ __forceinline__ int SW(int r) {
  return ((r & 3) << 3) | (r & 4) | ((r >> 3) * 3);
}

// ---------------- K0a: W1 (f32, [K=2048][N=1024]) -> Wt (bf16, [N][K]) ----------------
__global__ __launch_bounds__(256)
void convT_kernel(const float* __restrict__ W, unsigned short* __restrict__ Wt) {
  __shared__ unsigned short t[32][33];
  const int tx = threadIdx.x & 31;
  const int ty = threadIdx.x >> 5;          // 0..7
  const int nb = blockIdx.x * 32;           // n base
  const int kb = blockIdx.y * 32;           // k base
#pragma unroll
  for (int i = 0; i < 32; i += 8)
    t[ty + i][tx] = f2bf(W[(size_t)(kb + ty + i) * DFC + nb + tx]);
  __syncthreads();
#pragma unroll
  for (int i = 0; i < 32; i += 8)
    Wt[(size_t)(nb + ty + i) * DIN + kb + tx] = t[tx][ty + i];
}

// ---------------- K0b: Wsh (f32 [1024][20]) -> WshT (bf16 [32][1024], rows>=20 zero) ----
__global__ __launch_bounds__(256)
void convW2_kernel(const float* __restrict__ Wsh, unsigned short* __restrict__ WshT) {
  const int idx = blockIdx.x * 256 + threadIdx.x;   // 128 blocks -> 32768
  const int j = idx >> 10, k = idx & 1023;
  WshT[idx] = (j < 20) ? f2bf(Wsh[(size_t)k * 20 + j]) : (unsigned short)0;
}

// ---------------- K0c: A (f32 [16384][2048]) -> Ab (bf16, same layout) ----------------
__global__ __launch_bounds__(256)
void convA_kernel(const float* __restrict__ A, unsigned short* __restrict__ Ab) {
  const size_t total = (size_t)B_ * DIN;
  size_t idx = ((size_t)blockIdx.x * 256 + threadIdx.x) * 8;
  const size_t stride = (size_t)gridDim.x * 256 * 8;
  for (; idx < total; idx += stride) {
    f32x4 a = *(const f32x4*)(A + idx);
    f32x4 b = *(const f32x4*)(A + idx + 4);
    ushort8 o;
    o[0] = f2bf(a[0]); o[1] = f2bf(a[1]); o[2] = f2bf(a[2]); o[3] = f2bf(a[3]);
    o[4] = f2bf(b[0]); o[5] = f2bf(b[1]); o[6] = f2bf(b[2]); o[7] = f2bf(b[3]);
    *(ushort8*)(Ab + idx) = o;
  }
}

// ---------------- K1: x = elu(Ab @ Wt^T + b1); fused partial x@Wsh ----------------
// 256x256 tile, 8 waves (2M x 4N). BK=32 double-buffered (64KB LDS ->
// 2 blocks/CU): 2 phases/tile, each {reads+stage -> BAR+sched_barrier ->
// setprio 16 MFMA -> BAR}; one vmcnt(0)/tile after P2's MFMA — the drain is
// covered by the co-resident block's compute (m97/m114 mechanism).
// Slice layout: verified 16KB scheme (128 lrows x 8 chunks; chunk p of lrow
// holds (row=lrow*2+(q>>2), kc=q&3), q=p^(lrow&7)); linear gload dest,
// inverse-swizzled global source. Epilogue (r11): x stays on-chip.
__global__ __launch_bounds__(512, 2)
void gemm1_kernel(const unsigned short* __restrict__ Ab, const unsigned short* __restrict__ Bt,
                  const unsigned short* __restrict__ WshT, const float* __restrict__ b1,
                  float* __restrict__ part) {
  __shared__ unsigned short sT[2][2][8192];  // [dbuf][A=0/B=1] 64KB
  const int tid  = threadIdx.x;
  const int wave = tid >> 6, lane = tid & 63;
  const int wm = wave >> 2, wn = wave & 3;      // 2M x 4N waves, wave tile 128x64
  const int b = blockIdx.x;                     // 256 blocks
  const int tile = (b & 7) * 32 + (b >> 3);     // XCD-chunked bijection
  const int mtile = tile >> 2, ntile = tile & 3;
  const int rowBase = mtile * 256, colBase = ntile * 256;

  f32x4 acc[8][4] = {};
  bf16x8 a0[4], a1[4], bfr[4];

  const int lrow0 = wave * 16 + (lane >> 3);
  const int q     = (lane & 7) ^ (lrow0 & 7);
  const unsigned short* gA = Ab + (size_t)(rowBase + lrow0 * 2 + (q >> 2)) * DIN + (q & 3) * 8;
  const unsigned short* gB = Bt + (size_t)(colBase + lrow0 * 2 + (q >> 2)) * DIN + (q & 3) * 8;
  const int ldOff = wave * 1024;

  const int frow = lane & 15, hi = lane >> 4, fr2 = frow >> 1;
  const int pp    = ((frow & 1) * 4 + hi) ^ fr2;
  const int aBase = (wm * 64 + fr2) * 64 + pp * 8;
  const int bBase = (wn * 32 + fr2) * 64 + pp * 8;

#define STG(opv, db, kt) do {                                               \
    const unsigned short* g_ = ((opv) ? gB : gA) + (kt) * 32;               \
    unsigned short* l_ = &sT[db][opv][ldOff];                               \
    gload_lds16(g_, l_);                                                    \
    gload_lds16(g_ + (size_t)16 * DIN, l_ + 512);                           \
  } while (0)
#define RDA4(db, mq, dst) do {                                              \
    const unsigned short* s_ = &sT[db][0][aBase + (mq) * 2048];             \
    dst[0] = *(const bf16x8*)(s_);        dst[1] = *(const bf16x8*)(s_ + 512); \
    dst[2] = *(const bf16x8*)(s_ + 1024); dst[3] = *(const bf16x8*)(s_ + 1536); \
  } while (0)
#define RDB4(db, dst) do {                                                  \
    const unsigned short* s_ = &sT[db][1][bBase];                           \
    dst[0] = *(const bf16x8*)(s_);        dst[1] = *(const bf16x8*)(s_ + 512); \
    dst[2] = *(const bf16x8*)(s_ + 1024); dst[3] = *(const bf16x8*)(s_ + 1536); \
  } while (0)
#define MMH(MB, Ar) do {                                                    \
    __builtin_amdgcn_s_setprio(1);                                          \
    _Pragma("unroll") for (int mm = 0; mm < 4; ++mm)                        \
    _Pragma("unroll") for (int nn = 0; nn < 4; ++nn)                        \
      acc[(MB)+mm][nn] = __builtin_amdgcn_mfma_f32_16x16x32_bf16(           \
          Ar[mm], bfr[nn], acc[(MB)+mm][nn], 0, 0, 0);                      \
    __builtin_amdgcn_s_setprio(0);                                          \
  } while (0)
#define FENCE asm volatile("" ::: "memory")
#define BARP do { FENCE; __builtin_amdgcn_s_barrier();                      \
                  __builtin_amdgcn_sched_barrier(0); } while (0)

  // prologue: tile 0 -> buf 0
  STG(0, 0, 0); STG(1, 0, 0);
  asm volatile("s_waitcnt vmcnt(0)" ::: "memory");
  BARP;

  const int NT = DIN / 32;  // 64
#pragma unroll 2
  for (int t = 0; t < NT; ++t) {
    const int db = t & 1, dn = db ^ 1;
    // P1: reads {A mq0, B}, stage A(t+1)
    RDA4(db, 0, a0); RDB4(db, bfr);
    if (t < NT - 1) STG(0, dn, t + 1);
    BARP;
    MMH(0, a0);
    BARP;
    // P2: reads {A mq1}, stage B(t+1), drain after MFMA
    RDA4(db, 1, a1);
    if (t < NT - 1) STG(1, dn, t + 1);
    BARP;
    MMH(4, a1);
    if (t < NT - 1) asm volatile("s_waitcnt vmcnt(0)" ::: "memory");
    BARP;
  }
#undef STG
#undef RDA4
#undef RDB4
#undef MMH

  // ================= fused epilogue (r11, verified) =================
  const int ec0l = wn * 64 + frow;
  float bv[4];
#pragma unroll
  for (int n = 0; n < 4; ++n) bv[n] = b1[colBase + ec0l + n * 16];

  unsigned short* sX = (unsigned short*)sT;  // 64KB: [128 lrows][32 chunks of 8 bf16]
  BARP;

#pragma unroll
  for (int h = 0; h < 2; ++h) {
#pragma unroll
    for (int mm = 0; mm < 4; ++mm) {
#pragma unroll
      for (int n = 0; n < 4; ++n) {
#pragma unroll
        for (int r = 0; r < 4; ++r) {
          float v = acc[h * 4 + mm][n][r] + bv[n];
          v = v > 0.f ? v : expm1f(v);
          const int lrow = wm * 64 + mm * 16 + hi * 4 + r;   // 0..127
          const int cel  = ec0l + n * 16;                    // local col 0..255
          const int p    = (cel >> 3) ^ SW(lrow & 15);
          sX[lrow * 256 + p * 8 + (cel & 7)] = f2bf(v);
        }
      }
    }
    BARP;
    f32x4 acc2[2] = {};
    const int rb = wave * 16;
#pragma unroll
    for (int ks = 0; ks < 8; ++ks) {
      const int p = (ks * 4 + hi) ^ SW(frow);
      bf16x8 xa = *(const bf16x8*)&sX[(rb + frow) * 256 + p * 8];
      bf16x8 w0 = *(const bf16x8*)(WshT + (size_t)frow * DFC + colBase + ks * 32 + hi * 8);
      bf16x8 w1 = *(const bf16x8*)(WshT + (size_t)(16 + frow) * DFC + colBase + ks * 32 + hi * 8);
      acc2[0] = __builtin_amdgcn_mfma_f32_16x16x32_bf16(xa, w0, acc2[0], 0, 0, 0);
      acc2[1] = __builtin_amdgcn_mfma_f32_16x16x32_bf16(xa, w1, acc2[1], 0, 0, 0);
    }
#pragma unroll
    for (int jf = 0; jf < 2; ++jf) {
      const int j = jf * 16 + frow;
      if (j < 20) {
#pragma unroll
        for (int r = 0; r < 4; ++r) {
          const int lrow = rb + hi * 4 + r;                  // 0..127
          const int grow = rowBase + h * 64 + (lrow & 63) + (lrow >> 6) * 128;
          part[(size_t)ntile * (B_ * 20) + (size_t)grow * 20 + j] = acc2[jf][r];
        }
      }
    }
    BARP;
  }
}

// ---------------- K2: reduce partials + bias -> d_out (mode | log_std) ----------------
__global__ __launch_bounds__(256)
void reduce2_kernel(const float* __restrict__ part, const float* __restrict__ bsh,
                    float* __restrict__ out) {
  const int idx = blockIdx.x * 256 + threadIdx.x;  // 1280 blocks x 256 = 327680
  if (idx >= B_ * 20) return;
  const int row = idx / 20, j = idx - row * 20;
  float s = bsh[j];
#pragma unroll
  for (int t = 0; t < 4; ++t) s += part[(size_t)t * (B_ * 20) + idx];
  const int jj = j < 10 ? j : j - 10;
  const size_t base = (j < 10) ? (size_t)0 : (size_t)B_ * NB_;
  out[base + (size_t)row * NB_ + jj] = s;
}

// ---------------- K3: samples = mode + exp(log_std) * noise ----------------
__global__ __launch_bounds__(256)
void sample_kernel(const float* __restrict__ noise, float* __restrict__ out) {
  __shared__ float sm[4][NB_], se[4][NB_];
  const int tid  = threadIdx.x;
  const int wave = tid >> 6, lane = tid & 63;
  const int row  = blockIdx.x * 4 + wave;
  if (lane < NB_) {
    sm[wave][lane] = out[(size_t)row * NB_ + lane];
    se[wave][lane] = expf(out[(size_t)B_ * NB_ + (size_t)row * NB_ + lane]);
  }
  __syncthreads();
  const f32x4* np4 = (const f32x4*)(noise + (size_t)row * (S_ * NB_));
  f32x4*       op4 = (f32x4*)(out + (size_t)2 * B_ * NB_ + (size_t)row * (S_ * NB_));
#pragma unroll
  for (int it = 0; it < (S_ * NB_) / 256; ++it) {   // 10 iters
    f32x4 nv = np4[it * 64 + lane];
    int j0 = (lane * 4 + it * 6) % 10;
    int j1 = j0 + 1; if (j1 >= 10) j1 -= 10;
    int j2 = j1 + 1; if (j2 >= 10) j2 -= 10;
    int j3 = j2 + 1; if (j3 >= 10) j3 -= 10;
    f32x4 r;
    r[0] = sm[wave][j0] + se[wave][j0] * nv[0];
    r[1] = sm[wave][j1] + se[wave][j1] * nv[1];
    r[2] = sm[wave][j2] + se[wave][j2] * nv[2];
    r[3] = sm[wave][j3] + se[wave][j3] * nv[3];
    op4[it * 64 + lane] = r;
  }
}

extern "C" void kernel_launch(void* const* d_in, const int* in_sizes, int n_in,
                              void* d_out, int out_size, void* d_ws, size_t ws_size,
                              hipStream_t stream) {
  const float* A     = (const float*)d_in[0];  // [16384][2048]
  const float* W1    = (const float*)d_in[1];  // [2048][1024]
  const float* b1    = (const float*)d_in[2];  // [1024]
  const float* Wsh   = (const float*)d_in[3];  // [1024][20]
  const float* bsh   = (const float*)d_in[4];  // [20]
  const float* noise = (const float*)d_in[5];  // [16384][256][10]
  float* out = (float*)d_out;                  // mode | log_std | samples

  unsigned short* Wt   = (unsigned short*)d_ws;        // bf16 [1024][2048] = 4 MB
  unsigned short* WshT = Wt + (size_t)DFC * DIN;       // bf16 [32][1024] = 64 KB
  const size_t wsNeed = (size_t)DFC * DIN * 2 + 65536 +
                        (size_t)4 * B_ * 20 * 4 + (size_t)B_ * DIN * 2;
  float* part;
  unsigned short* Ab;
  if (ws_size >= wsNeed) {
    part = (float*)(WshT + 32 * 1024);
    Ab   = (unsigned short*)(part + (size_t)4 * B_ * 20);
  } else {
    part = out + (size_t)2 * B_ * NB_;
    Ab   = (unsigned short*)(part + (size_t)4 * B_ * 20);
  }

  convT_kernel<<<dim3(DFC / 32, DIN / 32), 256, 0, stream>>>(W1, Wt);
  convW2_kernel<<<dim3(128), 256, 0, stream>>>(Wsh, WshT);
  convA_kernel<<<dim3(2048), 256, 0, stream>>>(A, Ab);
  gemm1_kernel<<<dim3((B_ / 256) * (DFC / 256)), 512, 0, stream>>>(Ab, Wt, WshT, b1, part);
  reduce2_kernel<<<dim3((B_ * 20 + 255) / 256), 256, 0, stream>>>(part, bsh, out);
  sample_kernel<<<dim3(B_ / 4), 256, 0, stream>>>(noise, out);
}

// Round 14
// 183.004 us; speedup vs baseline: 1.0187x; 1.0187x over previous
//
#include <hip/hip_runtime.h>
#include <stdint.h>

using f32x4  = __attribute__((ext_vector_type(4))) float;
using bf16x8 = __attribute__((ext_vector_type(8))) short;
using ushort8 = __attribute__((ext_vector_type(8))) unsigned short;

#define B_   16384
#define S_   256
#define DIN  2048
#define DFC  1024
#define NB_  10

// f32 -> bf16 round-to-nearest-even
__device__ __forceinline__ unsigned short f2bf(float f) {
  union { float f; unsigned int u; } v; v.f = f;
  unsigned int u = v.u;
  unsigned int r = (u + 0x7FFFu + ((u >> 16) & 1u)) >> 16;
  return (unsigned short)r;
}

// async global->LDS, 16B per lane. LDS dest is wave-uniform base + lane*16;
// global source address is per-lane.
__device__ __forceinline__ void gload_lds16(const void* g, void* l) {
  __builtin_amdgcn_global_load_lds(
      (const __attribute__((address_space(1))) unsigned int*)g,
      (__attribute__((address_space(3))) unsigned int*)l, 16, 0, 0);
}

// epilogue-LDS swizzle (verified r11): chunk c of row r at pos c ^ SW(r&15).
__device__ __forceinline__ int SW(int r) {
  return ((r & 3) << 3) | (r & 4) | ((r >> 3) * 3);
}

// ---------------- K0a: W1 (f32, [K=2048][N=1024]) -> Wt (bf16, [N][K]) ----------------
__global__ __launch_bounds__(256)
void convT_kernel(const float* __restrict__ W, unsigned short* __restrict__ Wt) {
  __shared__ unsigned short t[32][33];
  const int tx = threadIdx.x & 31;
  const int ty = threadIdx.x >> 5;          // 0..7
  const int nb = blockIdx.x * 32;           // n base
  const int kb = blockIdx.y * 32;           // k base
#pragma unroll
  for (int i = 0; i < 32; i += 8)
    t[ty + i][tx] = f2bf(W[(size_t)(kb + ty + i) * DFC + nb + tx]);
  __syncthreads();
#pragma unroll
  for (int i = 0; i < 32; i += 8)
    Wt[(size_t)(nb + ty + i) * DIN + kb + tx] = t[tx][ty + i];
}

// ---------------- K0b: Wsh (f32 [1024][20]) -> WshT (bf16 [32][1024], rows>=20 zero) ----
__global__ __launch_bounds__(256)
void convW2_kernel(const float* __restrict__ Wsh, unsigned short* __restrict__ WshT) {
  const int idx = blockIdx.x * 256 + threadIdx.x;   // 128 blocks -> 32768
  const int j = idx >> 10, k = idx & 1023;
  WshT[idx] = (j < 20) ? f2bf(Wsh[(size_t)k * 20 + j]) : (unsigned short)0;
}

// ---------------- K0c: A (f32 [16384][2048]) -> Ab (bf16, same layout) ----------------
__global__ __launch_bounds__(256)
void convA_kernel(const float* __restrict__ A, unsigned short* __restrict__ Ab) {
  const size_t total = (size_t)B_ * DIN;
  size_t idx = ((size_t)blockIdx.x * 256 + threadIdx.x) * 8;
  const size_t stride = (size_t)gridDim.x * 256 * 8;
  for (; idx < total; idx += stride) {
    f32x4 a = *(const f32x4*)(A + idx);
    f32x4 b = *(const f32x4*)(A + idx + 4);
    ushort8 o;
    o[0] = f2bf(a[0]); o[1] = f2bf(a[1]); o[2] = f2bf(a[2]); o[3] = f2bf(a[3]);
    o[4] = f2bf(b[0]); o[5] = f2bf(b[1]); o[6] = f2bf(b[2]); o[7] = f2bf(b[3]);
    *(ushort8*)(Ab + idx) = o;
  }
}

// ---------------- K1: x = elu(Ab @ Wt^T + b1); fused partial x@Wsh ----------------
// 256x256 tile, 8 waves (2M x 4N), BK=64, dbuf ks-slices (128KB).
// Template-faithful phases: 4/tile, each {reads+stage -> BAR+sched_barrier ->
// setprio 16 MFMA (one quadrant x K=64) -> BAR}. Stages: P1/P2 = ks1(t+1),
// P4 = ks0(t+2) both ops. Counted vmcnt(4) once/tile at P4.
// Epilogue (r11, verified): x stays on-chip; partial x@Wsh per block.
__global__ __launch_bounds__(512, 2)
void gemm1_kernel(const unsigned short* __restrict__ Ab, const unsigned short* __restrict__ Bt,
                  const unsigned short* __restrict__ WshT, const float* __restrict__ b1,
                  float* __restrict__ part) {
  __shared__ unsigned short sT[2][2][2][8192];  // [dbuf][A=0/B=1][ks] 128KB
  const int tid  = threadIdx.x;
  const int wave = tid >> 6, lane = tid & 63;
  const int wm = wave >> 2, wn = wave & 3;      // 2M x 4N waves, wave tile 128x64
  const int b = blockIdx.x;                     // 256 blocks
  const int tile = (b & 7) * 32 + (b >> 3);     // XCD-chunked bijection
  const int mtile = tile >> 2, ntile = tile & 3;
  const int rowBase = mtile * 256, colBase = ntile * 256;

  f32x4 acc[8][4] = {};
  bf16x8 a0[4], a1[4];   // current A quadrant, ks0/ks1 (mi0 in P1-2, mi1 in P3-4)
  bf16x8 b0[2], b1v[2];  // B ni0, ks0/ks1
  bf16x8 c0[2], c1[2];   // B ni1, ks0/ks1

  const int lrow0 = wave * 16 + (lane >> 3);
  const int q     = (lane & 7) ^ (lrow0 & 7);
  const unsigned short* gA = Ab + (size_t)(rowBase + lrow0 * 2 + (q >> 2)) * DIN + (q & 3) * 8;
  const unsigned short* gB = Bt + (size_t)(colBase + lrow0 * 2 + (q >> 2)) * DIN + (q & 3) * 8;
  const int ldOff = wave * 1024;

  const int frow = lane & 15, hi = lane >> 4, fr2 = frow >> 1;
  const int pp    = ((frow & 1) * 4 + hi) ^ fr2;
  const int aBase = (wm * 64 + fr2) * 64 + pp * 8;
  const int bBase = (wn * 32 + fr2) * 64 + pp * 8;

#define STAGE(opv, db, ksv, kt) do {                                        \
    const unsigned short* g_ = ((opv) ? gB : gA) + (kt) * 64 + (ksv) * 32;  \
    unsigned short* l_ = &sT[db][opv][ksv][ldOff];                          \
    gload_lds16(g_, l_);                                                    \
    gload_lds16(g_ + (size_t)16 * DIN, l_ + 512);                           \
  } while (0)
#define RDA4(db, ksv, mq, dst) do {                                         \
    const unsigned short* s_ = &sT[db][0][ksv][aBase + (mq) * 2048];        \
    dst[0] = *(const bf16x8*)(s_);        dst[1] = *(const bf16x8*)(s_ + 512); \
    dst[2] = *(const bf16x8*)(s_ + 1024); dst[3] = *(const bf16x8*)(s_ + 1536); \
  } while (0)
#define RDB2(db, ksv, ni, dst) do {                                         \
    const unsigned short* s_ = &sT[db][1][ksv][bBase + (ni) * 1024];        \
    dst[0] = *(const bf16x8*)(s_);        dst[1] = *(const bf16x8*)(s_ + 512); \
  } while (0)
#define MMQ(MB, NB0, X0, X1) do {                                           \
    __builtin_amdgcn_s_setprio(1);                                          \
    _Pragma("unroll") for (int mm = 0; mm < 4; ++mm)                        \
    _Pragma("unroll") for (int nn = 0; nn < 2; ++nn) {                      \
      acc[(MB)+mm][(NB0)+nn] = __builtin_amdgcn_mfma_f32_16x16x32_bf16(     \
          a0[mm], X0[nn], acc[(MB)+mm][(NB0)+nn], 0, 0, 0);                 \
      acc[(MB)+mm][(NB0)+nn] = __builtin_amdgcn_mfma_f32_16x16x32_bf16(     \
          a1[mm], X1[nn], acc[(MB)+mm][(NB0)+nn], 0, 0, 0);                 \
    }                                                                       \
    __builtin_amdgcn_s_setprio(0);                                          \
  } while (0)
#define FENCE asm volatile("" ::: "memory")
#define BARP do { FENCE; __builtin_amdgcn_s_barrier();                      \
                  __builtin_amdgcn_sched_barrier(0); } while (0)

  // prologue: ks0(0)A,B ; ks1(0)A,B ; ks0(1)A,B — vmcnt(2) drains tile0 only
  STAGE(0, 0, 0, 0); STAGE(1, 0, 0, 0);
  STAGE(0, 0, 1, 0); STAGE(1, 0, 1, 0);
  STAGE(0, 1, 0, 1); STAGE(1, 1, 0, 1);
  asm volatile("s_waitcnt vmcnt(2)" ::: "memory");
  BARP;

  const int NT = DIN / 64;  // 32
#pragma unroll 2
  for (int t = 0; t < NT; ++t) {
    const int db = t & 1, dn = db ^ 1;
    // P1: Q(mi0,ni0) — 12 reads
    RDA4(db, 0, 0, a0); RDA4(db, 1, 0, a1);
    RDB2(db, 0, 0, b0); RDB2(db, 1, 0, b1v);
    if (t < NT - 1) STAGE(0, dn, 1, t + 1);
    BARP;
    MMQ(0, 0, b0, b1v);
    BARP;
    // P2: Q(mi0,ni1) — 4 reads
    RDB2(db, 0, 1, c0); RDB2(db, 1, 1, c1);
    if (t < NT - 1) STAGE(1, dn, 1, t + 1);
    BARP;
    MMQ(0, 2, c0, c1);
    BARP;
    // P3: Q(mi1,ni0) — 8 reads
    RDA4(db, 0, 1, a0); RDA4(db, 1, 1, a1);
    BARP;
    MMQ(4, 0, b0, b1v);
    BARP;
    // P4: Q(mi1,ni1) — 0 reads; stage ks0(t+2) both ops
    if (t < NT - 2) { STAGE(0, db, 0, t + 2); STAGE(1, db, 0, t + 2); }
    BARP;
    MMQ(4, 2, c0, c1);
    if (t < NT - 2)       asm volatile("s_waitcnt vmcnt(4)" ::: "memory");
    else if (t == NT - 2) asm volatile("s_waitcnt vmcnt(0)" ::: "memory");
    BARP;
  }
#undef STAGE
#undef RDA4
#undef RDB2
#undef MMQ

  // ================= fused epilogue (r11, verified) =================
  const int ec0l = wn * 64 + frow;
  float bv[4];
#pragma unroll
  for (int n = 0; n < 4; ++n) bv[n] = b1[colBase + ec0l + n * 16];

  unsigned short* sX = (unsigned short*)sT;  // 64KB: [128 lrows][32 chunks of 8 bf16]
  BARP;

#pragma unroll
  for (int h = 0; h < 2; ++h) {
#pragma unroll
    for (int mm = 0; mm < 4; ++mm) {
#pragma unroll
      for (int n = 0; n < 4; ++n) {
#pragma unroll
        for (int r = 0; r < 4; ++r) {
          float v = acc[h * 4 + mm][n][r] + bv[n];
          v = v > 0.f ? v : expm1f(v);
          const int lrow = wm * 64 + mm * 16 + hi * 4 + r;   // 0..127
          const int cel  = ec0l + n * 16;                    // local col 0..255
          const int p    = (cel >> 3) ^ SW(lrow & 15);
          sX[lrow * 256 + p * 8 + (cel & 7)] = f2bf(v);
        }
      }
    }
    BARP;
    f32x4 acc2[2] = {};
    const int rb = wave * 16;
#pragma unroll
    for (int ks = 0; ks < 8; ++ks) {
      const int p = (ks * 4 + hi) ^ SW(frow);
      bf16x8 xa = *(const bf16x8*)&sX[(rb + frow) * 256 + p * 8];
      bf16x8 w0 = *(const bf16x8*)(WshT + (size_t)frow * DFC + colBase + ks * 32 + hi * 8);
      bf16x8 w1 = *(const bf16x8*)(WshT + (size_t)(16 + frow) * DFC + colBase + ks * 32 + hi * 8);
      acc2[0] = __builtin_amdgcn_mfma_f32_16x16x32_bf16(xa, w0, acc2[0], 0, 0, 0);
      acc2[1] = __builtin_amdgcn_mfma_f32_16x16x32_bf16(xa, w1, acc2[1], 0, 0, 0);
    }
#pragma unroll
    for (int jf = 0; jf < 2; ++jf) {
      const int j = jf * 16 + frow;
      if (j < 20) {
#pragma unroll
        for (int r = 0; r < 4; ++r) {
          const int lrow = rb + hi * 4 + r;                  // 0..127
          const int grow = rowBase + h * 64 + (lrow & 63) + (lrow >> 6) * 128;
          part[(size_t)ntile * (B_ * 20) + (size_t)grow * 20 + j] = acc2[jf][r];
        }
      }
    }
    BARP;
  }
}

// ---------------- K2: reduce partials + bias -> d_out (mode | log_std) ----------------
__global__ __launch_bounds__(256)
void reduce2_kernel(const float* __restrict__ part, const float* __restrict__ bsh,
                    float* __restrict__ out) {
  const int idx = blockIdx.x * 256 + threadIdx.x;  // 1280 blocks x 256 = 327680
  if (idx >= B_ * 20) return;
  const int row = idx / 20, j = idx - row * 20;
  float s = bsh[j];
#pragma unroll
  for (int t = 0; t < 4; ++t) s += part[(size_t)t * (B_ * 20) + idx];
  const int jj = j < 10 ? j : j - 10;
  const size_t base = (j < 10) ? (size_t)0 : (size_t)B_ * NB_;
  out[base + (size_t)row * NB_ + jj] = s;
}

// ---------------- K3: samples = mode + exp(log_std) * noise ----------------
__global__ __launch_bounds__(256)
void sample_kernel(const float* __restrict__ noise, float* __restrict__ out) {
  __shared__ float sm[4][NB_], se[4][NB_];
  const int tid  = threadIdx.x;
  const int wave = tid >> 6, lane = tid & 63;
  const int row  = blockIdx.x * 4 + wave;
  if (lane < NB_) {
    sm[wave][lane] = out[(size_t)row * NB_ + lane];
    se[wave][lane] = expf(out[(size_t)B_ * NB_ + (size_t)row * NB_ + lane]);
  }
  __syncthreads();
  const f32x4* np4 = (const f32x4*)(noise + (size_t)row * (S_ * NB_));
  f32x4*       op4 = (f32x4*)(out + (size_t)2 * B_ * NB_ + (size_t)row * (S_ * NB_));
#pragma unroll
  for (int it = 0; it < (S_ * NB_) / 256; ++it) {   // 10 iters
    f32x4 nv = np4[it * 64 + lane];
    int j0 = (lane * 4 + it * 6) % 10;
    int j1 = j0 + 1; if (j1 >= 10) j1 -= 10;
    int j2 = j1 + 1; if (j2 >= 10) j2 -= 10;
    int j3 = j2 + 1; if (j3 >= 10) j3 -= 10;
    f32x4 r;
    r[0] = sm[wave][j0] + se[wave][j0] * nv[0];
    r[1] = sm[wave][j1] + se[wave][j1] * nv[1];
    r[2] = sm[wave][j2] + se[wave][j2] * nv[2];
    r[3] = sm[wave][j3] + se[wave][j3] * nv[3];
    op4[it * 64 + lane] = r;
  }
}

extern "C" void kernel_launch(void* const* d_in, const int* in_sizes, int n_in,
                              void* d_out, int out_size, void* d_ws, size_t ws_size,
                              hipStream_t stream) {
  const float* A     = (const float*)d_in[0];  // [16384][2048]
  const float* W1    = (const float*)d_in[1];  // [2048][1024]
  const float* b1    = (const float*)d_in[2];  // [1024]
  const float* Wsh   = (const float*)d_in[3];  // [1024][20]
  const float* bsh   = (const float*)d_in[4];  // [20]
  const float* noise = (const float*)d_in[5];  // [16384][256][10]
  float* out = (float*)d_out;                  // mode | log_std | samples

  unsigned short* Wt   = (unsigned short*)d_ws;        // bf16 [1024][2048] = 4 MB
  unsigned short* WshT = Wt + (size_t)DFC * DIN;       // bf16 [32][1024] = 64 KB
  const size_t wsNeed = (size_t)DFC * DIN * 2 + 65536 +
                        (size_t)4 * B_ * 20 * 4 + (size_t)B_ * DIN * 2;
  float* part;
  unsigned short* Ab;
  if (ws_size >= wsNeed) {
    part = (float*)(WshT + 32 * 1024);
    Ab   = (unsigned short*)(part + (size_t)4 * B_ * 20);
  } else {
    part = out + (size_t)2 * B_ * NB_;
    Ab   = (unsigned short*)(part + (size_t)4 * B_ * 20);
  }

  convT_kernel<<<dim3(DFC / 32, DIN / 32), 256, 0, stream>>>(W1, Wt);
  convW2_kernel<<<dim3(128), 256, 0, stream>>>(Wsh, WshT);
  convA_kernel<<<dim3(2048), 256, 0, stream>>>(A, Ab);
  gemm1_kernel<<<dim3((B_ / 256) * (DFC / 256)), 512, 0, stream>>>(Ab, Wt, WshT, b1, part);
  reduce2_kernel<<<dim3((B_ * 20 + 255) / 256), 256, 0, stream>>>(part, bsh, out);
  sample_kernel<<<dim3(B_ / 4), 256, 0, stream>>>(noise, out);
}

// Round 16
// 182.814 us; speedup vs baseline: 1.0198x; 1.0010x over previous
//
#include <hip/hip_runtime.h>
#include <stdint.h>

using f32x4  = __attribute__((ext_vector_type(4))) float;
using bf16x8 = __attribute__((ext_vector_type(8))) short;
using ushort8 = __attribute__((ext_vector_type(8))) unsigned short;

#define B_   16384
#define S_   256
#define DIN  2048
#define DFC  1024
#define NB_  10

// f32 -> bf16 round-to-nearest-even
__device__ __forceinline__ unsigned short f2bf(float f) {
  union { float f; unsigned int u; } v; v.f = f;
  unsigned int u = v.u;
  unsigned int r = (u + 0x7FFFu + ((u >> 16) & 1u)) >> 16;
  return (unsigned short)r;
}

// async global->LDS, 16B per lane. LDS dest is wave-uniform base + lane*16;
// global source address is per-lane.
__device__ __forceinline__ void gload_lds16(const void* g, void* l) {
  __builtin_amdgcn_global_load_lds(
      (const __attribute__((address_space(1))) unsigned int*)g,
      (__attribute__((address_space(3))) unsigned int*)l, 16, 0, 0);
}

// epilogue-LDS swizzle (verified r11): chunk c of row r at pos c ^ SW(r&15).
__device__ __forceinline__ int SW(int r) {
  return ((r & 3) << 3) | (r & 4) | ((r >> 3) * 3);
}

// ---------------- K0a: W1 (f32, [K=2048][N=1024]) -> Wt (bf16, [N][K]) ----------------
__global__ __launch_bounds__(256)
void convT_kernel(const float* __restrict__ W, unsigned short* __restrict__ Wt) {
  __shared__ unsigned short t[32][33];
  const int tx = threadIdx.x & 31;
  const int ty = threadIdx.x >> 5;          // 0..7
  const int nb = blockIdx.x * 32;           // n base
  const int kb = blockIdx.y * 32;           // k base
#pragma unroll
  for (int i = 0; i < 32; i += 8)
    t[ty + i][tx] = f2bf(W[(size_t)(kb + ty + i) * DFC + nb + tx]);
  __syncthreads();
#pragma unroll
  for (int i = 0; i < 32; i += 8)
    Wt[(size_t)(nb + ty + i) * DIN + kb + tx] = t[tx][ty + i];
}

// ---------------- K0b: Wsh (f32 [1024][20]) -> WshT (bf16 [32][1024], rows>=20 zero) ----
__global__ __launch_bounds__(256)
void convW2_kernel(const float* __restrict__ Wsh, unsigned short* __restrict__ WshT) {
  const int idx = blockIdx.x * 256 + threadIdx.x;   // 128 blocks -> 32768
  const int j = idx >> 10, k = idx & 1023;
  WshT[idx] = (j < 20) ? f2bf(Wsh[(size_t)k * 20 + j]) : (unsigned short)0;
}

// ---------------- K0c: A (f32 [16384][2048]) -> Ab (bf16, same layout) ----------------
__global__ __launch_bounds__(256)
void convA_kernel(const float* __restrict__ A, unsigned short* __restrict__ Ab) {
  const size_t total = (size_t)B_ * DIN;
  size_t idx = ((size_t)blockIdx.x * 256 + threadIdx.x) * 8;
  const size_t stride = (size_t)gridDim.x * 256 * 8;
  for (; idx < total; idx += stride) {
    f32x4 a = *(const f32x4*)(A + idx);
    f32x4 b = *(const f32x4*)(A + idx + 4);
    ushort8 o;
    o[0] = f2bf(a[0]); o[1] = f2bf(a[1]); o[2] = f2bf(a[2]); o[3] = f2bf(a[3]);
    o[4] = f2bf(b[0]); o[5] = f2bf(b[1]); o[6] = f2bf(b[2]); o[7] = f2bf(b[3]);
    *(ushort8*)(Ab + idx) = o;
  }
}

// ---------------- K1: x = elu(Ab @ Wt^T + b1); fused partial x@Wsh ----------------
// 256x256 tile, 8 waves (2M x 4N), BK=64, dbuf ks-slices (128KB).
// Template-faithful phases: 4/tile, each {reads+stage -> BAR+sched_barrier ->
// setprio 16 MFMA (one quadrant x K=64) -> BAR}. Stages: P1/P2 = ks1(t+1),
// P4 = ks0(t+2) both ops. Counted vmcnt(4) once/tile at P4.
// Epilogue (r11, verified): x stays on-chip; partial x@Wsh per block.
__global__ __launch_bounds__(512, 2)
void gemm1_kernel(const unsigned short* __restrict__ Ab, const unsigned short* __restrict__ Bt,
                  const unsigned short* __restrict__ WshT, const float* __restrict__ b1,
                  float* __restrict__ part) {
  __shared__ unsigned short sT[2][2][2][8192];  // [dbuf][A=0/B=1][ks] 128KB
  const int tid  = threadIdx.x;
  const int wave = tid >> 6, lane = tid & 63;
  const int wm = wave >> 2, wn = wave & 3;      // 2M x 4N waves, wave tile 128x64
  const int b = blockIdx.x;                     // 256 blocks
  const int tile = (b & 7) * 32 + (b >> 3);     // XCD-chunked bijection
  const int mtile = tile >> 2, ntile = tile & 3;
  const int rowBase = mtile * 256, colBase = ntile * 256;

  f32x4 acc[8][4] = {};
  bf16x8 a0[4], a1[4];   // current A quadrant, ks0/ks1 (mi0 in P1-2, mi1 in P3-4)
  bf16x8 b0[2], b1v[2];  // B ni0, ks0/ks1
  bf16x8 c0[2], c1[2];   // B ni1, ks0/ks1

  const int lrow0 = wave * 16 + (lane >> 3);
  const int q     = (lane & 7) ^ (lrow0 & 7);
  const unsigned short* gA = Ab + (size_t)(rowBase + lrow0 * 2 + (q >> 2)) * DIN + (q & 3) * 8;
  const unsigned short* gB = Bt + (size_t)(colBase + lrow0 * 2 + (q >> 2)) * DIN + (q & 3) * 8;
  const int ldOff = wave * 1024;

  const int frow = lane & 15, hi = lane >> 4, fr2 = frow >> 1;
  const int pp    = ((frow & 1) * 4 + hi) ^ fr2;
  const int aBase = (wm * 64 + fr2) * 64 + pp * 8;
  const int bBase = (wn * 32 + fr2) * 64 + pp * 8;

#define STAGE(opv, db, ksv, kt) do {                                        \
    const unsigned short* g_ = ((opv) ? gB : gA) + (kt) * 64 + (ksv) * 32;  \
    unsigned short* l_ = &sT[db][opv][ksv][ldOff];                          \
    gload_lds16(g_, l_);                                                    \
    gload_lds16(g_ + (size_t)16 * DIN, l_ + 512);                           \
  } while (0)
#define RDA4(db, ksv, mq, dst) do {                                         \
    const unsigned short* s_ = &sT[db][0][ksv][aBase + (mq) * 2048];        \
    dst[0] = *(const bf16x8*)(s_);        dst[1] = *(const bf16x8*)(s_ + 512); \
    dst[2] = *(const bf16x8*)(s_ + 1024); dst[3] = *(const bf16x8*)(s_ + 1536); \
  } while (0)
#define RDB2(db, ksv, ni, dst) do {                                         \
    const unsigned short* s_ = &sT[db][1][ksv][bBase + (ni) * 1024];        \
    dst[0] = *(const bf16x8*)(s_);        dst[1] = *(const bf16x8*)(s_ + 512); \
  } while (0)
#define MMQ(MB, NB0, X0, X1) do {                                           \
    __builtin_amdgcn_s_setprio(1);                                          \
    _Pragma("unroll") for (int mm = 0; mm < 4; ++mm)                        \
    _Pragma("unroll") for (int nn = 0; nn < 2; ++nn) {                      \
      acc[(MB)+mm][(NB0)+nn] = __builtin_amdgcn_mfma_f32_16x16x32_bf16(     \
          a0[mm], X0[nn], acc[(MB)+mm][(NB0)+nn], 0, 0, 0);                 \
      acc[(MB)+mm][(NB0)+nn] = __builtin_amdgcn_mfma_f32_16x16x32_bf16(     \
          a1[mm], X1[nn], acc[(MB)+mm][(NB0)+nn], 0, 0, 0);                 \
    }                                                                       \
    __builtin_amdgcn_s_setprio(0);                                          \
  } while (0)
#define FENCE asm volatile("" ::: "memory")
#define BARP do { FENCE; __builtin_amdgcn_s_barrier();                      \
                  __builtin_amdgcn_sched_barrier(0); } while (0)

  // prologue: ks0(0)A,B ; ks1(0)A,B ; ks0(1)A,B — vmcnt(2) drains tile0 only
  STAGE(0, 0, 0, 0); STAGE(1, 0, 0, 0);
  STAGE(0, 0, 1, 0); STAGE(1, 0, 1, 0);
  STAGE(0, 1, 0, 1); STAGE(1, 1, 0, 1);
  asm volatile("s_waitcnt vmcnt(2)" ::: "memory");
  BARP;

  const int NT = DIN / 64;  // 32
#pragma unroll 2
  for (int t = 0; t < NT; ++t) {
    const int db = t & 1, dn = db ^ 1;
    // P1: Q(mi0,ni0) — 12 reads
    RDA4(db, 0, 0, a0); RDA4(db, 1, 0, a1);
    RDB2(db, 0, 0, b0); RDB2(db, 1, 0, b1v);
    if (t < NT - 1) STAGE(0, dn, 1, t + 1);
    BARP;
    MMQ(0, 0, b0, b1v);
    BARP;
    // P2: Q(mi0,ni1) — 4 reads
    RDB2(db, 0, 1, c0); RDB2(db, 1, 1, c1);
    if (t < NT - 1) STAGE(1, dn, 1, t + 1);
    BARP;
    MMQ(0, 2, c0, c1);
    BARP;
    // P3: Q(mi1,ni0) — 8 reads
    RDA4(db, 0, 1, a0); RDA4(db, 1, 1, a1);
    BARP;
    MMQ(4, 0, b0, b1v);
    BARP;
    // P4: Q(mi1,ni1) — 0 reads; stage ks0(t+2) both ops
    if (t < NT - 2) { STAGE(0, db, 0, t + 2); STAGE(1, db, 0, t + 2); }
    BARP;
    MMQ(4, 2, c0, c1);
    if (t < NT - 2)       asm volatile("s_waitcnt vmcnt(4)" ::: "memory");
    else if (t == NT - 2) asm volatile("s_waitcnt vmcnt(0)" ::: "memory");
    BARP;
  }
#undef STAGE
#undef RDA4
#undef RDB2
#undef MMQ

  // ================= fused epilogue (r11, verified) =================
  const int ec0l = wn * 64 + frow;
  float bv[4];
#pragma unroll
  for (int n = 0; n < 4; ++n) bv[n] = b1[colBase + ec0l + n * 16];

  unsigned short* sX = (unsigned short*)sT;  // 64KB: [128 lrows][32 chunks of 8 bf16]
  BARP;

#pragma unroll
  for (int h = 0; h < 2; ++h) {
#pragma unroll
    for (int mm = 0; mm < 4; ++mm) {
#pragma unroll
      for (int n = 0; n < 4; ++n) {
#pragma unroll
        for (int r = 0; r < 4; ++r) {
          float v = acc[h * 4 + mm][n][r] + bv[n];
          v = v > 0.f ? v : expm1f(v);
          const int lrow = wm * 64 + mm * 16 + hi * 4 + r;   // 0..127
          const int cel  = ec0l + n * 16;                    // local col 0..255
          const int p    = (cel >> 3) ^ SW(lrow & 15);
          sX[lrow * 256 + p * 8 + (cel & 7)] = f2bf(v);
        }
      }
    }
    BARP;
    f32x4 acc2[2] = {};
    const int rb = wave * 16;
#pragma unroll
    for (int ks = 0; ks < 8; ++ks) {
      const int p = (ks * 4 + hi) ^ SW(frow);
      bf16x8 xa = *(const bf16x8*)&sX[(rb + frow) * 256 + p * 8];
      bf16x8 w0 = *(const bf16x8*)(WshT + (size_t)frow * DFC + colBase + ks * 32 + hi * 8);
      bf16x8 w1 = *(const bf16x8*)(WshT + (size_t)(16 + frow) * DFC + colBase + ks * 32 + hi * 8);
      acc2[0] = __builtin_amdgcn_mfma_f32_16x16x32_bf16(xa, w0, acc2[0], 0, 0, 0);
      acc2[1] = __builtin_amdgcn_mfma_f32_16x16x32_bf16(xa, w1, acc2[1], 0, 0, 0);
    }
#pragma unroll
    for (int jf = 0; jf < 2; ++jf) {
      const int j = jf * 16 + frow;
      if (j < 20) {
#pragma unroll
        for (int r = 0; r < 4; ++r) {
          const int lrow = rb + hi * 4 + r;                  // 0..127
          const int grow = rowBase + h * 64 + (lrow & 63) + (lrow >> 6) * 128;
          part[(size_t)ntile * (B_ * 20) + (size_t)grow * 20 + j] = acc2[jf][r];
        }
      }
    }
    BARP;
  }
}

// ---------------- K2: reduce partials + bias -> d_out (mode | log_std) ----------------
__global__ __launch_bounds__(256)
void reduce2_kernel(const float* __restrict__ part, const float* __restrict__ bsh,
                    float* __restrict__ out) {
  const int idx = blockIdx.x * 256 + threadIdx.x;  // 1280 blocks x 256 = 327680
  if (idx >= B_ * 20) return;
  const int row = idx / 20, j = idx - row * 20;
  float s = bsh[j];
#pragma unroll
  for (int t = 0; t < 4; ++t) s += part[(size_t)t * (B_ * 20) + idx];
  const int jj = j < 10 ? j : j - 10;
  const size_t base = (j < 10) ? (size_t)0 : (size_t)B_ * NB_;
  out[base + (size_t)row * NB_ + jj] = s;
}

// ---------------- K3: samples = mode + exp(log_std) * noise ----------------
__global__ __launch_bounds__(256)
void sample_kernel(const float* __restrict__ noise, float* __restrict__ out) {
  __shared__ float sm[4][NB_], se[4][NB_];
  const int tid  = threadIdx.x;
  const int wave = tid >> 6, lane = tid & 63;
  const int row  = blockIdx.x * 4 + wave;
  if (lane < NB_) {
    sm[wave][lane] = out[(size_t)row * NB_ + lane];
    se[wave][lane] = expf(out[(size_t)B_ * NB_ + (size_t)row * NB_ + lane]);
  }
  __syncthreads();
  const f32x4* np4 = (const f32x4*)(noise + (size_t)row * (S_ * NB_));
  f32x4*       op4 = (f32x4*)(out + (size_t)2 * B_ * NB_ + (size_t)row * (S_ * NB_));
#pragma unroll
  for (int it = 0; it < (S_ * NB_) / 256; ++it) {   // 10 iters
    f32x4 nv = np4[it * 64 + lane];
    int j0 = (lane * 4 + it * 6) % 10;
    int j1 = j0 + 1; if (j1 >= 10) j1 -= 10;
    int j2 = j1 + 1; if (j2 >= 10) j2 -= 10;
    int j3 = j2 + 1; if (j3 >= 10) j3 -= 10;
    f32x4 r;
    r[0] = sm[wave][j0] + se[wave][j0] * nv[0];
    r[1] = sm[wave][j1] + se[wave][j1] * nv[1];
    r[2] = sm[wave][j2] + se[wave][j2] * nv[2];
    r[3] = sm[wave][j3] + se[wave][j3] * nv[3];
    op4[it * 64 + lane] = r;
  }
}

extern "C" void kernel_launch(void* const* d_in, const int* in_sizes, int n_in,
                              void* d_out, int out_size, void* d_ws, size_t ws_size,
                              hipStream_t stream) {
  const float* A     = (const float*)d_in[0];  // [16384][2048]
  const float* W1    = (const float*)d_in[1];  // [2048][1024]
  const float* b1    = (const float*)d_in[2];  // [1024]
  const float* Wsh   = (const float*)d_in[3];  // [1024][20]
  const float* bsh   = (const float*)d_in[4];  // [20]
  const float* noise = (const float*)d_in[5];  // [16384][256][10]
  float* out = (float*)d_out;                  // mode | log_std | samples

  unsigned short* Wt   = (unsigned short*)d_ws;        // bf16 [1024][2048] = 4 MB
  unsigned short* WshT = Wt + (size_t)DFC * DIN;       // bf16 [32][1024] = 64 KB
  const size_t wsNeed = (size_t)DFC * DIN * 2 + 65536 +
                        (size_t)4 * B_ * 20 * 4 + (size_t)B_ * DIN * 2;
  float* part;
  unsigned short* Ab;
  if (ws_size >= wsNeed) {
    part = (float*)(WshT + 32 * 1024);
    Ab   = (unsigned short*)(part + (size_t)4 * B_ * 20);
  } else {
    part = out + (size_t)2 * B_ * NB_;
    Ab   = (unsigned short*)(part + (size_t)4 * B_ * 20);
  }

  convT_kernel<<<dim3(DFC / 32, DIN / 32), 256, 0, stream>>>(W1, Wt);
  convW2_kernel<<<dim3(128), 256, 0, stream>>>(Wsh, WshT);
  convA_kernel<<<dim3(2048), 256, 0, stream>>>(A, Ab);
  gemm1_kernel<<<dim3((B_ / 256) * (DFC / 256)), 512, 0, stream>>>(Ab, Wt, WshT, b1, part);
  reduce2_kernel<<<dim3((B_ * 20 + 255) / 256), 256, 0, stream>>>(part, bsh, out);
  sample_kernel<<<dim3(B_ / 4), 256, 0, stream>>>(noise, out);
}

// Round 17
// 180.336 us; speedup vs baseline: 1.0338x; 1.0137x over previous
//
#include <hip/hip_runtime.h>
#include <stdint.h>

using f32x4  = __attribute__((ext_vector_type(4))) float;
using bf16x8 = __attribute__((ext_vector_type(8))) short;
using ushort8 = __attribute__((ext_vector_type(8))) unsigned short;

#define B_   16384
#define S_   256
#define DIN  2048
#define DFC  1024
#define NB_  10

// f32 -> bf16 round-to-nearest-even
__device__ __forceinline__ unsigned short f2bf(float f) {
  union { float f; unsigned int u; } v; v.f = f;
  unsigned int u = v.u;
  unsigned int r = (u + 0x7FFFu + ((u >> 16) & 1u)) >> 16;
  return (unsigned short)r;
}

// async global->LDS, 16B per lane. LDS dest is wave-uniform base + lane*16;
// global source address is per-lane.
__device__ __forceinline__ void gload_lds16(const void* g, void* l) {
  __builtin_amdgcn_global_load_lds(
      (const __attribute__((address_space(1))) unsigned int*)g,
      (__attribute__((address_space(3))) unsigned int*)l, 16, 0, 0);
}

// epilogue-LDS swizzle (verified r11): chunk c of row r at pos c ^ SW(r&15).
__device__ __forceinline__ int SW(int r) {
  return ((r & 3) << 3) | (r & 4) | ((r >> 3) * 3);
}

// ---------------- K0a: W1 (f32, [K=2048][N=1024]) -> Wt (bf16, [N][K]) ----------------
__global__ __launch_bounds__(256)
void convT_kernel(const float* __restrict__ W, unsigned short* __restrict__ Wt) {
  __shared__ unsigned short t[32][33];
  const int tx = threadIdx.x & 31;
  const int ty = threadIdx.x >> 5;          // 0..7
  const int nb = blockIdx.x * 32;           // n base
  const int kb = blockIdx.y * 32;           // k base
#pragma unroll
  for (int i = 0; i < 32; i += 8)
    t[ty + i][tx] = f2bf(W[(size_t)(kb + ty + i) * DFC + nb + tx]);
  __syncthreads();
#pragma unroll
  for (int i = 0; i < 32; i += 8)
    Wt[(size_t)(nb + ty + i) * DIN + kb + tx] = t[tx][ty + i];
}

// ---------------- K0b: Wsh (f32 [1024][20]) -> WshT (bf16 [32][1024], rows>=20 zero) ----
__global__ __launch_bounds__(256)
void convW2_kernel(const float* __restrict__ Wsh, unsigned short* __restrict__ WshT) {
  const int idx = blockIdx.x * 256 + threadIdx.x;   // 128 blocks -> 32768
  const int j = idx >> 10, k = idx & 1023;
  WshT[idx] = (j < 20) ? f2bf(Wsh[(size_t)k * 20 + j]) : (unsigned short)0;
}

// ---------------- K0c: A (f32 [16384][2048]) -> Ab (bf16, same layout) ----------------
__global__ __launch_bounds__(256)
void convA_kernel(const float* __restrict__ A, unsigned short* __restrict__ Ab) {
  const size_t total = (size_t)B_ * DIN;
  size_t idx = ((size_t)blockIdx.x * 256 + threadIdx.x) * 8;
  const size_t stride = (size_t)gridDim.x * 256 * 8;
  for (; idx < total; idx += stride) {
    f32x4 a = *(const f32x4*)(A + idx);
    f32x4 b = *(const f32x4*)(A + idx + 4);
    ushort8 o;
    o[0] = f2bf(a[0]); o[1] = f2bf(a[1]); o[2] = f2bf(a[2]); o[3] = f2bf(a[3]);
    o[4] = f2bf(b[0]); o[5] = f2bf(b[1]); o[6] = f2bf(b[2]); o[7] = f2bf(b[3]);
    *(ushort8*)(Ab + idx) = o;
  }
}

// ---------------- K1: x = elu(Ab @ Wt^T + b1); fused partial x@Wsh ----------------
// 256x256 tile, 8 waves (2M x 4N), BK=64, dbuf ks-slices (128KB).
// Template-faithful phases: 4/tile, each {reads+stage -> BAR+sched_barrier ->
// setprio 16 MFMA (one quadrant x K=64) -> BAR}. Stages: P1/P2 = ks1(t+1),
// P4 = ks0(t+2) both ops. Counted vmcnt(4) once/tile at P4.
// Epilogue (r11, verified): x stays on-chip; partial x@Wsh per block.
// [BYTE-IDENTICAL to the r12/r14/r16 verified source — do not perturb.]
__global__ __launch_bounds__(512, 2)
void gemm1_kernel(const unsigned short* __restrict__ Ab, const unsigned short* __restrict__ Bt,
                  const unsigned short* __restrict__ WshT, const float* __restrict__ b1,
                  float* __restrict__ part) {
  __shared__ unsigned short sT[2][2][2][8192];  // [dbuf][A=0/B=1][ks] 128KB
  const int tid  = threadIdx.x;
  const int wave = tid >> 6, lane = tid & 63;
  const int wm = wave >> 2, wn = wave & 3;      // 2M x 4N waves, wave tile 128x64
  const int b = blockIdx.x;                     // 256 blocks
  const int tile = (b & 7) * 32 + (b >> 3);     // XCD-chunked bijection
  const int mtile = tile >> 2, ntile = tile & 3;
  const int rowBase = mtile * 256, colBase = ntile * 256;

  f32x4 acc[8][4] = {};
  bf16x8 a0[4], a1[4];   // current A quadrant, ks0/ks1 (mi0 in P1-2, mi1 in P3-4)
  bf16x8 b0[2], b1v[2];  // B ni0, ks0/ks1
  bf16x8 c0[2], c1[2];   // B ni1, ks0/ks1

  const int lrow0 = wave * 16 + (lane >> 3);
  const int q     = (lane & 7) ^ (lrow0 & 7);
  const unsigned short* gA = Ab + (size_t)(rowBase + lrow0 * 2 + (q >> 2)) * DIN + (q & 3) * 8;
  const unsigned short* gB = Bt + (size_t)(colBase + lrow0 * 2 + (q >> 2)) * DIN + (q & 3) * 8;
  const int ldOff = wave * 1024;

  const int frow = lane & 15, hi = lane >> 4, fr2 = frow >> 1;
  const int pp    = ((frow & 1) * 4 + hi) ^ fr2;
  const int aBase = (wm * 64 + fr2) * 64 + pp * 8;
  const int bBase = (wn * 32 + fr2) * 64 + pp * 8;

#define STAGE(opv, db, ksv, kt) do {                                        \
    const unsigned short* g_ = ((opv) ? gB : gA) + (kt) * 64 + (ksv) * 32;  \
    unsigned short* l_ = &sT[db][opv][ksv][ldOff];                          \
    gload_lds16(g_, l_);                                                    \
    gload_lds16(g_ + (size_t)16 * DIN, l_ + 512);                           \
  } while (0)
#define RDA4(db, ksv, mq, dst) do {                                         \
    const unsigned short* s_ = &sT[db][0][ksv][aBase + (mq) * 2048];        \
    dst[0] = *(const bf16x8*)(s_);        dst[1] = *(const bf16x8*)(s_ + 512); \
    dst[2] = *(const bf16x8*)(s_ + 1024); dst[3] = *(const bf16x8*)(s_ + 1536); \
  } while (0)
#define RDB2(db, ksv, ni, dst) do {                                         \
    const unsigned short* s_ = &sT[db][1][ksv][bBase + (ni) * 1024];        \
    dst[0] = *(const bf16x8*)(s_);        dst[1] = *(const bf16x8*)(s_ + 512); \
  } while (0)
#define MMQ(MB, NB0, X0, X1) do {                                           \
    __builtin_amdgcn_s_setprio(1);                                          \
    _Pragma("unroll") for (int mm = 0; mm < 4; ++mm)                        \
    _Pragma("unroll") for (int nn = 0; nn < 2; ++nn) {                      \
      acc[(MB)+mm][(NB0)+nn] = __builtin_amdgcn_mfma_f32_16x16x32_bf16(     \
          a0[mm], X0[nn], acc[(MB)+mm][(NB0)+nn], 0, 0, 0);                 \
      acc[(MB)+mm][(NB0)+nn] = __builtin_amdgcn_mfma_f32_16x16x32_bf16(     \
          a1[mm], X1[nn], acc[(MB)+mm][(NB0)+nn], 0, 0, 0);                 \
    }                                                                       \
    __builtin_amdgcn_s_setprio(0);                                          \
  } while (0)
#define FENCE asm volatile("" ::: "memory")
#define BARP do { FENCE; __builtin_amdgcn_s_barrier();                      \
                  __builtin_amdgcn_sched_barrier(0); } while (0)

  // prologue: ks0(0)A,B ; ks1(0)A,B ; ks0(1)A,B — vmcnt(2) drains tile0 only
  STAGE(0, 0, 0, 0); STAGE(1, 0, 0, 0);
  STAGE(0, 0, 1, 0); STAGE(1, 0, 1, 0);
  STAGE(0, 1, 0, 1); STAGE(1, 1, 0, 1);
  asm volatile("s_waitcnt vmcnt(2)" ::: "memory");
  BARP;

  const int NT = DIN / 64;  // 32
#pragma unroll 2
  for (int t = 0; t < NT; ++t) {
    const int db = t & 1, dn = db ^ 1;
    // P1: Q(mi0,ni0) — 12 reads
    RDA4(db, 0, 0, a0); RDA4(db, 1, 0, a1);
    RDB2(db, 0, 0, b0); RDB2(db, 1, 0, b1v);
    if (t < NT - 1) STAGE(0, dn, 1, t + 1);
    BARP;
    MMQ(0, 0, b0, b1v);
    BARP;
    // P2: Q(mi0,ni1) — 4 reads
    RDB2(db, 0, 1, c0); RDB2(db, 1, 1, c1);
    if (t < NT - 1) STAGE(1, dn, 1, t + 1);
    BARP;
    MMQ(0, 2, c0, c1);
    BARP;
    // P3: Q(mi1,ni0) — 8 reads
    RDA4(db, 0, 1, a0); RDA4(db, 1, 1, a1);
    BARP;
    MMQ(4, 0, b0, b1v);
    BARP;
    // P4: Q(mi1,ni1) — 0 reads; stage ks0(t+2) both ops
    if (t < NT - 2) { STAGE(0, db, 0, t + 2); STAGE(1, db, 0, t + 2); }
    BARP;
    MMQ(4, 2, c0, c1);
    if (t < NT - 2)       asm volatile("s_waitcnt vmcnt(4)" ::: "memory");
    else if (t == NT - 2) asm volatile("s_waitcnt vmcnt(0)" ::: "memory");
    BARP;
  }
#undef STAGE
#undef RDA4
#undef RDB2
#undef MMQ

  // ================= fused epilogue (r11, verified) =================
  const int ec0l = wn * 64 + frow;
  float bv[4];
#pragma unroll
  for (int n = 0; n < 4; ++n) bv[n] = b1[colBase + ec0l + n * 16];

  unsigned short* sX = (unsigned short*)sT;  // 64KB: [128 lrows][32 chunks of 8 bf16]
  BARP;

#pragma unroll
  for (int h = 0; h < 2; ++h) {
#pragma unroll
    for (int mm = 0; mm < 4; ++mm) {
#pragma unroll
      for (int n = 0; n < 4; ++n) {
#pragma unroll
        for (int r = 0; r < 4; ++r) {
          float v = acc[h * 4 + mm][n][r] + bv[n];
          v = v > 0.f ? v : expm1f(v);
          const int lrow = wm * 64 + mm * 16 + hi * 4 + r;   // 0..127
          const int cel  = ec0l + n * 16;                    // local col 0..255
          const int p    = (cel >> 3) ^ SW(lrow & 15);
          sX[lrow * 256 + p * 8 + (cel & 7)] = f2bf(v);
        }
      }
    }
    BARP;
    f32x4 acc2[2] = {};
    const int rb = wave * 16;
#pragma unroll
    for (int ks = 0; ks < 8; ++ks) {
      const int p = (ks * 4 + hi) ^ SW(frow);
      bf16x8 xa = *(const bf16x8*)&sX[(rb + frow) * 256 + p * 8];
      bf16x8 w0 = *(const bf16x8*)(WshT + (size_t)frow * DFC + colBase + ks * 32 + hi * 8);
      bf16x8 w1 = *(const bf16x8*)(WshT + (size_t)(16 + frow) * DFC + colBase + ks * 32 + hi * 8);
      acc2[0] = __builtin_amdgcn_mfma_f32_16x16x32_bf16(xa, w0, acc2[0], 0, 0, 0);
      acc2[1] = __builtin_amdgcn_mfma_f32_16x16x32_bf16(xa, w1, acc2[1], 0, 0, 0);
    }
#pragma unroll
    for (int jf = 0; jf < 2; ++jf) {
      const int j = jf * 16 + frow;
      if (j < 20) {
#pragma unroll
        for (int r = 0; r < 4; ++r) {
          const int lrow = rb + hi * 4 + r;                  // 0..127
          const int grow = rowBase + h * 64 + (lrow & 63) + (lrow >> 6) * 128;
          part[(size_t)ntile * (B_ * 20) + (size_t)grow * 20 + j] = acc2[jf][r];
        }
      }
    }
    BARP;
  }
}

// ---------------- K3: fused reduce + sampling ----------------
// One wave per row. Lanes 0..19 reduce the 4 ntile-partials + bias, write
// mode/log_std to d_out, and fill the LDS broadcast arrays; then all 64 lanes
// stream samples = mode + exp(log_std) * noise (f32x4, 10 iters).
__global__ __launch_bounds__(256)
void sample_kernel(const float* __restrict__ part, const float* __restrict__ bsh,
                   const float* __restrict__ noise, float* __restrict__ out) {
  __shared__ float sm[4][NB_], se[4][NB_];
  const int tid  = threadIdx.x;
  const int wave = tid >> 6, lane = tid & 63;
  const int row  = blockIdx.x * 4 + wave;
  if (lane < 20) {
    const int j = lane;
    float s = bsh[j];
#pragma unroll
    for (int t = 0; t < 4; ++t) s += part[(size_t)t * (B_ * 20) + (size_t)row * 20 + j];
    if (j < 10) {
      out[(size_t)row * NB_ + j] = s;
      sm[wave][j] = s;
    } else {
      out[(size_t)B_ * NB_ + (size_t)row * NB_ + (j - 10)] = s;
      se[wave][j - 10] = expf(s);
    }
  }
  __syncthreads();
  const f32x4* np4 = (const f32x4*)(noise + (size_t)row * (S_ * NB_));
  f32x4*       op4 = (f32x4*)(out + (size_t)2 * B_ * NB_ + (size_t)row * (S_ * NB_));
#pragma unroll
  for (int it = 0; it < (S_ * NB_) / 256; ++it) {   // 10 iters
    f32x4 nv = np4[it * 64 + lane];
    int j0 = (lane * 4 + it * 6) % 10;
    int j1 = j0 + 1; if (j1 >= 10) j1 -= 10;
    int j2 = j1 + 1; if (j2 >= 10) j2 -= 10;
    int j3 = j2 + 1; if (j3 >= 10) j3 -= 10;
    f32x4 r;
    r[0] = sm[wave][j0] + se[wave][j0] * nv[0];
    r[1] = sm[wave][j1] + se[wave][j1] * nv[1];
    r[2] = sm[wave][j2] + se[wave][j2] * nv[2];
    r[3] = sm[wave][j3] + se[wave][j3] * nv[3];
    op4[it * 64 + lane] = r;
  }
}

extern "C" void kernel_launch(void* const* d_in, const int* in_sizes, int n_in,
                              void* d_out, int out_size, void* d_ws, size_t ws_size,
                              hipStream_t stream) {
  const float* A     = (const float*)d_in[0];  // [16384][2048]
  const float* W1    = (const float*)d_in[1];  // [2048][1024]
  const float* b1    = (const float*)d_in[2];  // [1024]
  const float* Wsh   = (const float*)d_in[3];  // [1024][20]
  const float* bsh   = (const float*)d_in[4];  // [20]
  const float* noise = (const float*)d_in[5];  // [16384][256][10]
  float* out = (float*)d_out;                  // mode | log_std | samples

  unsigned short* Wt   = (unsigned short*)d_ws;        // bf16 [1024][2048] = 4 MB
  unsigned short* WshT = Wt + (size_t)DFC * DIN;       // bf16 [32][1024] = 64 KB
  const size_t wsNeed = (size_t)DFC * DIN * 2 + 65536 +
                        (size_t)4 * B_ * 20 * 4 + (size_t)B_ * DIN * 2;
  float* part;
  unsigned short* Ab;
  if (ws_size >= wsNeed) {
    part = (float*)(WshT + 32 * 1024);
    Ab   = (unsigned short*)(part + (size_t)4 * B_ * 20);
  } else {
    part = out + (size_t)2 * B_ * NB_;
    Ab   = (unsigned short*)(part + (size_t)4 * B_ * 20);
  }

  convT_kernel<<<dim3(DFC / 32, DIN / 32), 256, 0, stream>>>(W1, Wt);
  convW2_kernel<<<dim3(128), 256, 0, stream>>>(Wsh, WshT);
  convA_kernel<<<dim3(2048), 256, 0, stream>>>(A, Ab);
  gemm1_kernel<<<dim3((B_ / 256) * (DFC / 256)), 512, 0, stream>>>(Ab, Wt, WshT, b1, part);
  sample_kernel<<<dim3(B_ / 4), 256, 0, stream>>>(part, bsh, noise, out);
}

// Round 18
// 175.844 us; speedup vs baseline: 1.0602x; 1.0255x over previous
//
#include <hip/hip_runtime.h>
#include <stdint.h>

using f32x4  = __attribute__((ext_vector_type(4))) float;
using bf16x8 = __attribute__((ext_vector_type(8))) short;
using ushort8 = __attribute__((ext_vector_type(8))) unsigned short;

#define B_   16384
#define S_   256
#define DIN  2048
#define DFC  1024
#define NB_  10

// f32 -> bf16 round-to-nearest-even
__device__ __forceinline__ unsigned short f2bf(float f) {
  union { float f; unsigned int u; } v; v.f = f;
  unsigned int u = v.u;
  unsigned int r = (u + 0x7FFFu + ((u >> 16) & 1u)) >> 16;
  return (unsigned short)r;
}

// async global->LDS, 16B per lane. LDS dest is wave-uniform base + lane*16;
// global source address is per-lane.
__device__ __forceinline__ void gload_lds16(const void* g, void* l) {
  __builtin_amdgcn_global_load_lds(
      (const __attribute__((address_space(1))) unsigned int*)g,
      (__attribute__((address_space(3))) unsigned int*)l, 16, 0, 0);
}

// epilogue-LDS swizzle (verified r11): chunk c of row r at pos c ^ SW(r&15).
__device__ __forceinline__ int SW(int r) {
  return ((r & 3) << 3) | (r & 4) | ((r >> 3) * 3);
}

// ---------------- K0: merged prologue — convA + convT + convW2 in one dispatch ----------------
// blocks [0,2048):    A (f32 [16384][2048]) -> Ab (bf16, same layout), grid-stride
// blocks [2048,4096): W1 (f32 [K=2048][N=1024]) -> Wt (bf16 [N][K]) via LDS transpose
// blocks [4096,4224): Wsh (f32 [1024][20]) -> WshT (bf16 [32][1024], rows>=20 zero)
__global__ __launch_bounds__(256)
void conv_all_kernel(const float* __restrict__ A, unsigned short* __restrict__ Ab,
                     const float* __restrict__ W, unsigned short* __restrict__ Wt,
                     const float* __restrict__ Wsh, unsigned short* __restrict__ WshT) {
  __shared__ unsigned short t[32][33];
  const int blk = blockIdx.x;
  if (blk < 2048) {
    // ---- convA (grid-stride over 2048 virtual blocks) ----
    const size_t total = (size_t)B_ * DIN;
    size_t idx = ((size_t)blk * 256 + threadIdx.x) * 8;
    const size_t stride = (size_t)2048 * 256 * 8;
    for (; idx < total; idx += stride) {
      f32x4 a = *(const f32x4*)(A + idx);
      f32x4 b = *(const f32x4*)(A + idx + 4);
      ushort8 o;
      o[0] = f2bf(a[0]); o[1] = f2bf(a[1]); o[2] = f2bf(a[2]); o[3] = f2bf(a[3]);
      o[4] = f2bf(b[0]); o[5] = f2bf(b[1]); o[6] = f2bf(b[2]); o[7] = f2bf(b[3]);
      *(ushort8*)(Ab + idx) = o;
    }
  } else if (blk < 4096) {
    // ---- convT: bx in [0,2048), nb = (bx%32)*32, kb = (bx/32)*32 ----
    const int bx = blk - 2048;
    const int tx = threadIdx.x & 31;
    const int ty = threadIdx.x >> 5;          // 0..7
    const int nb = (bx & 31) * 32;            // n base (DFC/32 = 32)
    const int kb = (bx >> 5) * 32;            // k base (DIN/32 = 64)
#pragma unroll
    for (int i = 0; i < 32; i += 8)
      t[ty + i][tx] = f2bf(W[(size_t)(kb + ty + i) * DFC + nb + tx]);
    __syncthreads();
#pragma unroll
    for (int i = 0; i < 32; i += 8)
      Wt[(size_t)(nb + ty + i) * DIN + kb + tx] = t[tx][ty + i];
  } else {
    // ---- convW2: bx in [0,128) -> 32768 elems ----
    const int idx = (blk - 4096) * 256 + threadIdx.x;
    const int j = idx >> 10, k = idx & 1023;
    WshT[idx] = (j < 20) ? f2bf(Wsh[(size_t)k * 20 + j]) : (unsigned short)0;
  }
}

// ---------------- K1: x = elu(Ab @ Wt^T + b1); fused partial x@Wsh ----------------
// 256x256 tile, 8 waves (2M x 4N), BK=64, dbuf ks-slices (128KB).
// Template-faithful phases: 4/tile, each {reads+stage -> BAR+sched_barrier ->
// setprio 16 MFMA (one quadrant x K=64) -> BAR}. Stages: P1/P2 = ks1(t+1),
// P4 = ks0(t+2) both ops. Counted vmcnt(4) once/tile at P4.
// Epilogue (r11, verified): x stays on-chip; partial x@Wsh per block.
// [BYTE-IDENTICAL to the r12/r14/r16/r17 verified source — do not perturb.]
__global__ __launch_bounds__(512, 2)
void gemm1_kernel(const unsigned short* __restrict__ Ab, const unsigned short* __restrict__ Bt,
                  const unsigned short* __restrict__ WshT, const float* __restrict__ b1,
                  float* __restrict__ part) {
  __shared__ unsigned short sT[2][2][2][8192];  // [dbuf][A=0/B=1][ks] 128KB
  const int tid  = threadIdx.x;
  const int wave = tid >> 6, lane = tid & 63;
  const int wm = wave >> 2, wn = wave & 3;      // 2M x 4N waves, wave tile 128x64
  const int b = blockIdx.x;                     // 256 blocks
  const int tile = (b & 7) * 32 + (b >> 3);     // XCD-chunked bijection
  const int mtile = tile >> 2, ntile = tile & 3;
  const int rowBase = mtile * 256, colBase = ntile * 256;

  f32x4 acc[8][4] = {};
  bf16x8 a0[4], a1[4];   // current A quadrant, ks0/ks1 (mi0 in P1-2, mi1 in P3-4)
  bf16x8 b0[2], b1v[2];  // B ni0, ks0/ks1
  bf16x8 c0[2], c1[2];   // B ni1, ks0/ks1

  const int lrow0 = wave * 16 + (lane >> 3);
  const int q     = (lane & 7) ^ (lrow0 & 7);
  const unsigned short* gA = Ab + (size_t)(rowBase + lrow0 * 2 + (q >> 2)) * DIN + (q & 3) * 8;
  const unsigned short* gB = Bt + (size_t)(colBase + lrow0 * 2 + (q >> 2)) * DIN + (q & 3) * 8;
  const int ldOff = wave * 1024;

  const int frow = lane & 15, hi = lane >> 4, fr2 = frow >> 1;
  const int pp    = ((frow & 1) * 4 + hi) ^ fr2;
  const int aBase = (wm * 64 + fr2) * 64 + pp * 8;
  const int bBase = (wn * 32 + fr2) * 64 + pp * 8;

#define STAGE(opv, db, ksv, kt) do {                                        \
    const unsigned short* g_ = ((opv) ? gB : gA) + (kt) * 64 + (ksv) * 32;  \
    unsigned short* l_ = &sT[db][opv][ksv][ldOff];                          \
    gload_lds16(g_, l_);                                                    \
    gload_lds16(g_ + (size_t)16 * DIN, l_ + 512);                           \
  } while (0)
#define RDA4(db, ksv, mq, dst) do {                                         \
    const unsigned short* s_ = &sT[db][0][ksv][aBase + (mq) * 2048];        \
    dst[0] = *(const bf16x8*)(s_);        dst[1] = *(const bf16x8*)(s_ + 512); \
    dst[2] = *(const bf16x8*)(s_ + 1024); dst[3] = *(const bf16x8*)(s_ + 1536); \
  } while (0)
#define RDB2(db, ksv, ni, dst) do {                                         \
    const unsigned short* s_ = &sT[db][1][ksv][bBase + (ni) * 1024];        \
    dst[0] = *(const bf16x8*)(s_);        dst[1] = *(const bf16x8*)(s_ + 512); \
  } while (0)
#define MMQ(MB, NB0, X0, X1) do {                                           \
    __builtin_amdgcn_s_setprio(1);                                          \
    _Pragma("unroll") for (int mm = 0; mm < 4; ++mm)                        \
    _Pragma("unroll") for (int nn = 0; nn < 2; ++nn) {                      \
      acc[(MB)+mm][(NB0)+nn] = __builtin_amdgcn_mfma_f32_16x16x32_bf16(     \
          a0[mm], X0[nn], acc[(MB)+mm][(NB0)+nn], 0, 0, 0);                 \
      acc[(MB)+mm][(NB0)+nn] = __builtin_amdgcn_mfma_f32_16x16x32_bf16(     \
          a1[mm], X1[nn], acc[(MB)+mm][(NB0)+nn], 0, 0, 0);                 \
    }                                                                       \
    __builtin_amdgcn_s_setprio(0);                                          \
  } while (0)
#define FENCE asm volatile("" ::: "memory")
#define BARP do { FENCE; __builtin_amdgcn_s_barrier();                      \
                  __builtin_amdgcn_sched_barrier(0); } while (0)

  // prologue: ks0(0)A,B ; ks1(0)A,B ; ks0(1)A,B — vmcnt(2) drains tile0 only
  STAGE(0, 0, 0, 0); STAGE(1, 0, 0, 0);
  STAGE(0, 0, 1, 0); STAGE(1, 0, 1, 0);
  STAGE(0, 1, 0, 1); STAGE(1, 1, 0, 1);
  asm volatile("s_waitcnt vmcnt(2)" ::: "memory");
  BARP;

  const int NT = DIN / 64;  // 32
#pragma unroll 2
  for (int t = 0; t < NT; ++t) {
    const int db = t & 1, dn = db ^ 1;
    // P1: Q(mi0,ni0) — 12 reads
    RDA4(db, 0, 0, a0); RDA4(db, 1, 0, a1);
    RDB2(db, 0, 0, b0); RDB2(db, 1, 0, b1v);
    if (t < NT - 1) STAGE(0, dn, 1, t + 1);
    BARP;
    MMQ(0, 0, b0, b1v);
    BARP;
    // P2: Q(mi0,ni1) — 4 reads
    RDB2(db, 0, 1, c0); RDB2(db, 1, 1, c1);
    if (t < NT - 1) STAGE(1, dn, 1, t + 1);
    BARP;
    MMQ(0, 2, c0, c1);
    BARP;
    // P3: Q(mi1,ni0) — 8 reads
    RDA4(db, 0, 1, a0); RDA4(db, 1, 1, a1);
    BARP;
    MMQ(4, 0, b0, b1v);
    BARP;
    // P4: Q(mi1,ni1) — 0 reads; stage ks0(t+2) both ops
    if (t < NT - 2) { STAGE(0, db, 0, t + 2); STAGE(1, db, 0, t + 2); }
    BARP;
    MMQ(4, 2, c0, c1);
    if (t < NT - 2)       asm volatile("s_waitcnt vmcnt(4)" ::: "memory");
    else if (t == NT - 2) asm volatile("s_waitcnt vmcnt(0)" ::: "memory");
    BARP;
  }
#undef STAGE
#undef RDA4
#undef RDB2
#undef MMQ

  // ================= fused epilogue (r11, verified) =================
  const int ec0l = wn * 64 + frow;
  float bv[4];
#pragma unroll
  for (int n = 0; n < 4; ++n) bv[n] = b1[colBase + ec0l + n * 16];

  unsigned short* sX = (unsigned short*)sT;  // 64KB: [128 lrows][32 chunks of 8 bf16]
  BARP;

#pragma unroll
  for (int h = 0; h < 2; ++h) {
#pragma unroll
    for (int mm = 0; mm < 4; ++mm) {
#pragma unroll
      for (int n = 0; n < 4; ++n) {
#pragma unroll
        for (int r = 0; r < 4; ++r) {
          float v = acc[h * 4 + mm][n][r] + bv[n];
          v = v > 0.f ? v : expm1f(v);
          const int lrow = wm * 64 + mm * 16 + hi * 4 + r;   // 0..127
          const int cel  = ec0l + n * 16;                    // local col 0..255
          const int p    = (cel >> 3) ^ SW(lrow & 15);
          sX[lrow * 256 + p * 8 + (cel & 7)] = f2bf(v);
        }
      }
    }
    BARP;
    f32x4 acc2[2] = {};
    const int rb = wave * 16;
#pragma unroll
    for (int ks = 0; ks < 8; ++ks) {
      const int p = (ks * 4 + hi) ^ SW(frow);
      bf16x8 xa = *(const bf16x8*)&sX[(rb + frow) * 256 + p * 8];
      bf16x8 w0 = *(const bf16x8*)(WshT + (size_t)frow * DFC + colBase + ks * 32 + hi * 8);
      bf16x8 w1 = *(const bf16x8*)(WshT + (size_t)(16 + frow) * DFC + colBase + ks * 32 + hi * 8);
      acc2[0] = __builtin_amdgcn_mfma_f32_16x16x32_bf16(xa, w0, acc2[0], 0, 0, 0);
      acc2[1] = __builtin_amdgcn_mfma_f32_16x16x32_bf16(xa, w1, acc2[1], 0, 0, 0);
    }
#pragma unroll
    for (int jf = 0; jf < 2; ++jf) {
      const int j = jf * 16 + frow;
      if (j < 20) {
#pragma unroll
        for (int r = 0; r < 4; ++r) {
          const int lrow = rb + hi * 4 + r;                  // 0..127
          const int grow = rowBase + h * 64 + (lrow & 63) + (lrow >> 6) * 128;
          part[(size_t)ntile * (B_ * 20) + (size_t)grow * 20 + j] = acc2[jf][r];
        }
      }
    }
    BARP;
  }
}

// ---------------- K3: fused reduce + sampling ----------------
// One wave per row. Lanes 0..19 reduce the 4 ntile-partials + bias, write
// mode/log_std to d_out, and fill the LDS broadcast arrays; then all 64 lanes
// stream samples = mode + exp(log_std) * noise (f32x4, 10 iters).
__global__ __launch_bounds__(256)
void sample_kernel(const float* __restrict__ part, const float* __restrict__ bsh,
                   const float* __restrict__ noise, float* __restrict__ out) {
  __shared__ float sm[4][NB_], se[4][NB_];
  const int tid  = threadIdx.x;
  const int wave = tid >> 6, lane = tid & 63;
  const int row  = blockIdx.x * 4 + wave;
  if (lane < 20) {
    const int j = lane;
    float s = bsh[j];
#pragma unroll
    for (int t = 0; t < 4; ++t) s += part[(size_t)t * (B_ * 20) + (size_t)row * 20 + j];
    if (j < 10) {
      out[(size_t)row * NB_ + j] = s;
      sm[wave][j] = s;
    } else {
      out[(size_t)B_ * NB_ + (size_t)row * NB_ + (j - 10)] = s;
      se[wave][j - 10] = expf(s);
    }
  }
  __syncthreads();
  const f32x4* np4 = (const f32x4*)(noise + (size_t)row * (S_ * NB_));
  f32x4*       op4 = (f32x4*)(out + (size_t)2 * B_ * NB_ + (size_t)row * (S_ * NB_));
#pragma unroll
  for (int it = 0; it < (S_ * NB_) / 256; ++it) {   // 10 iters
    f32x4 nv = np4[it * 64 + lane];
    int j0 = (lane * 4 + it * 6) % 10;
    int j1 = j0 + 1; if (j1 >= 10) j1 -= 10;
    int j2 = j1 + 1; if (j2 >= 10) j2 -= 10;
    int j3 = j2 + 1; if (j3 >= 10) j3 -= 10;
    f32x4 r;
    r[0] = sm[wave][j0] + se[wave][j0] * nv[0];
    r[1] = sm[wave][j1] + se[wave][j1] * nv[1];
    r[2] = sm[wave][j2] + se[wave][j2] * nv[2];
    r[3] = sm[wave][j3] + se[wave][j3] * nv[3];
    op4[it * 64 + lane] = r;
  }
}

extern "C" void kernel_launch(void* const* d_in, const int* in_sizes, int n_in,
                              void* d_out, int out_size, void* d_ws, size_t ws_size,
                              hipStream_t stream) {
  const float* A     = (const float*)d_in[0];  // [16384][2048]
  const float* W1    = (const float*)d_in[1];  // [2048][1024]
  const float* b1    = (const float*)d_in[2];  // [1024]
  const float* Wsh   = (const float*)d_in[3];  // [1024][20]
  const float* bsh   = (const float*)d_in[4];  // [20]
  const float* noise = (const float*)d_in[5];  // [16384][256][10]
  float* out = (float*)d_out;                  // mode | log_std | samples

  unsigned short* Wt   = (unsigned short*)d_ws;        // bf16 [1024][2048] = 4 MB
  unsigned short* WshT = Wt + (size_t)DFC * DIN;       // bf16 [32][1024] = 64 KB
  const size_t wsNeed = (size_t)DFC * DIN * 2 + 65536 +
                        (size_t)4 * B_ * 20 * 4 + (size_t)B_ * DIN * 2;
  float* part;
  unsigned short* Ab;
  if (ws_size >= wsNeed) {
    part = (float*)(WshT + 32 * 1024);
    Ab   = (unsigned short*)(part + (size_t)4 * B_ * 20);
  } else {
    part = out + (size_t)2 * B_ * NB_;
    Ab   = (unsigned short*)(part + (size_t)4 * B_ * 20);
  }

  conv_all_kernel<<<dim3(4224), 256, 0, stream>>>(A, Ab, W1, Wt, Wsh, WshT);
  gemm1_kernel<<<dim3((B_ / 256) * (DFC / 256)), 512, 0, stream>>>(Ab, Wt, WshT, b1, part);
  sample_kernel<<<dim3(B_ / 4), 256, 0, stream>>>(part, bsh, noise, out);
}